// Round 6
// baseline (349.188 us; speedup 1.0000x reference)
//
#include <hip/hip_runtime.h>
#include <cmath>

// M=87, CLS=65, K=128, DL=DC=128, DO=2048, BD=256, B=256, HW=49

typedef __attribute__((ext_vector_type(8))) short short8;
typedef __attribute__((ext_vector_type(4))) short s16x4;
typedef __attribute__((ext_vector_type(4))) float f32x4;

// ---------------- workspace layout (float offsets) ----------------
constexpr size_t OFF_W12BF = 0;          // [128][2048] bf16
constexpr size_t OFF_T1BF  = 131072;     // [2048][128] bf16 (Wox2@Wox1)
constexpr size_t OFF_WBBF  = 262144;     // [256][2048] bf16
constexpr size_t OFF_XPBF  = 524288;     // [256][2048] bf16
constexpr size_t OFF_WAPBF = 786432;     // [224][128] bf16 (Wps;Wa;0)
constexpr size_t OFF_WG2BF = 800768;     // [128][128] bf16
constexpr size_t OFF_ENPBF = 808960;     // [96][96] bf16 edge_norm (symmetric)
constexpr size_t OFF_B215  = 813568;     // 224 f
constexpr size_t OFF_B12   = 813792;     // 128 f
constexpr size_t OFF_WPR   = 813920;     // 87x87 f
constexpr size_t OFF_BTMP  = 821496;     // 2048 f
constexpr size_t OFF_WC    = 823544;     // [256][128] f (atomic accum)
constexpr size_t OFF_BC    = 856312;     // 256 f
constexpr size_t OFF_VY    = 856568;     // 256x87 f
constexpr size_t OFF_NT    = 878848;     // [2][128][88] f
constexpr size_t OFF_PART  = 901376;     // [4][256][128][52] f partial xl

__device__ __forceinline__ unsigned short f2bf(float f) {
  unsigned u = __builtin_bit_cast(unsigned, f);
  u += 0x7fffu + ((u >> 16) & 1u);
  return (unsigned short)(u >> 16);
}
__device__ __forceinline__ float bf2f(unsigned short s) {
  return __builtin_bit_cast(float, ((unsigned)s) << 16);
}

// ---------------- ksetup_all: casts/inits + weight GEMMs + bias vecs ----------------
// block map: [0,256) WBBF8 | [256,320) featp4 | [320,352) Wc0 | [352,380) WAP4 |
// [380,396) WG2_4 | [396,432) ENP | [432,462) WPR | 462 b215 | [463,591) GEMM | [591,1135) btmp/b12
__global__ __launch_bounds__(256) void ksetup_all(
    const float* __restrict__ Wb,  const float* __restrict__ bb,
    const float* __restrict__ Wa,  const float* __restrict__ ba,
    const float* __restrict__ Wps, const float* __restrict__ bps,
    const float* __restrict__ Wg,  const float* __restrict__ edge,
    const float* __restrict__ Wo2, const float* __restrict__ Wo1,
    const float* __restrict__ Wox2,const float* __restrict__ Wox1,
    const float* __restrict__ box1,const float* __restrict__ box2,
    const float* __restrict__ bo1, const float* __restrict__ bo2,
    float* __restrict__ ws, float* __restrict__ featp)
{
  __shared__ alignas(16) short As[64*72];
  __shared__ alignas(16) short Bs[64*72];
  int blk = blockIdx.x, tid = threadIdx.x;
  if (blk < 256) {                         // WBBF cast, 8 elems/thread
    int base = (blk*256 + tid)*8;
    float4 v0 = *(const float4*)&Wb[base];
    float4 v1 = *(const float4*)&Wb[base+4];
    short8 sv;
    sv[0]=(short)f2bf(v0.x); sv[1]=(short)f2bf(v0.y); sv[2]=(short)f2bf(v0.z); sv[3]=(short)f2bf(v0.w);
    sv[4]=(short)f2bf(v1.x); sv[5]=(short)f2bf(v1.y); sv[6]=(short)f2bf(v1.z); sv[7]=(short)f2bf(v1.w);
    *(short8*)&((unsigned short*)(ws+OFF_WBBF))[base] = sv;
  } else if (blk < 320) {                  // featp init = bb, 4/thread
    int idx4 = ((blk-256)*256 + tid)*4;
    float4 bv = *(const float4*)&bb[idx4 & 255];
    *(float4*)&featp[idx4] = bv;
  } else if (blk < 352) {                  // zero Wc, 4/thread
    int idx4 = ((blk-320)*256 + tid)*4;
    float4 z; z.x=z.y=z.z=z.w=0.f;
    *(float4*)&ws[OFF_WC + idx4] = z;
  } else if (blk < 380) {                  // WAPBF [r=224][c=128], 4/thread
    int idx4 = ((blk-352)*256 + tid)*4;    // < 28672
    int r = idx4 >> 7, c = idx4 & 127;
    float4 v;
    if (r < 128)      v = *(const float4*)&Wps[r*128 + c];
    else if (r < 215) v = *(const float4*)&Wa[(r-128)*128 + c];
    else              { v.x=v.y=v.z=v.w=0.f; }
    s16x4 sv; sv[0]=(short)f2bf(v.x); sv[1]=(short)f2bf(v.y); sv[2]=(short)f2bf(v.z); sv[3]=(short)f2bf(v.w);
    *(s16x4*)&((unsigned short*)(ws+OFF_WAPBF))[idx4] = sv;
  } else if (blk < 396) {                  // WG2BF [o][d], 4/thread
    int idx4 = ((blk-380)*256 + tid)*4;    // < 16384
    int o = idx4 >> 7, d = idx4 & 127;
    float4 v = *(const float4*)&Wg[o*256 + 128 + d];
    s16x4 sv; sv[0]=(short)f2bf(v.x); sv[1]=(short)f2bf(v.y); sv[2]=(short)f2bf(v.z); sv[3]=(short)f2bf(v.w);
    *(s16x4*)&((unsigned short*)(ws+OFF_WG2BF))[idx4] = sv;
  } else if (blk < 432) {                  // ENPBF [96][96], zero-padded
    int idx = (blk-396)*256 + tid;         // < 9216
    int m = idx / 96, n = idx % 96;
    float v = 0.f;
    if (m < 87 && n < 87) {
      float sm = 0.f, sn = 0.f;
      for (int k = 0; k < 87; ++k) { sm += edge[k*87+m]; sn += edge[k*87+n]; }
      v = edge[m*87+n] / sqrtf(sm*sn);
    }
    ((unsigned short*)(ws+OFF_ENPBF))[idx] = f2bf(v);
  } else if (blk < 462) {                  // WPR fp32
    int idx = (blk-432)*256 + tid;
    if (idx < 87*87) {
      int j = idx % 87;
      float rs = 0.f;
      for (int k = 0; k < 87; ++k) rs += edge[j*87+k];
      ws[OFF_WPR + idx] = 0.85f * edge[idx] / rs;
    }
  } else if (blk == 462) {                 // b215 (pad 224)
    if (tid < 224) {
      float v = (tid < 128) ? bps[tid] : (tid < 215 ? ba[tid-128] : 0.f);
      ws[OFF_B215 + tid] = v;
    }
  } else if (blk < 591) {                  // ---- W12 / T1 MFMA tiles ----
    int gb = blk - 463;
    const float *A, *B; unsigned short* C; int lda, ldb, ldc, i0, j0;
    if (gb < 64) {   // W12 [128][2048] = Wo2@Wo1
      A = Wo2; B = Wo1; C = (unsigned short*)(ws+OFF_W12BF);
      lda = 512; ldb = 2048; ldc = 2048;
      i0 = (gb & 1)*64; j0 = (gb >> 1)*64;
    } else {         // T1 [2048][128] = Wox2@Wox1
      int b2 = gb - 64;
      A = Wox2; B = Wox1; C = (unsigned short*)(ws+OFF_T1BF);
      lda = 512; ldb = 128; ldc = 128;
      i0 = (b2 >> 1)*64; j0 = (b2 & 1)*64;
    }
    int w = tid >> 6, l = tid & 63, quad = l >> 4, lane16 = l & 15;
    f32x4 acc[4];
    #pragma unroll
    for (int i = 0; i < 4; ++i) acc[i] = (f32x4)(0.f);
    for (int kc = 0; kc < 512; kc += 64) {
      for (int t = tid; t < 1024; t += 256) {      // A stage [m][k]
        int r = t >> 4, k4 = t & 15;
        float4 v = *(const float4*)&A[(size_t)(i0+r)*lda + kc + k4*4];
        s16x4 sv; sv[0]=(short)f2bf(v.x); sv[1]=(short)f2bf(v.y); sv[2]=(short)f2bf(v.z); sv[3]=(short)f2bf(v.w);
        *(s16x4*)&As[r*72 + k4*4] = sv;
      }
      for (int t = tid; t < 1024; t += 256) {      // B transpose-stage -> [n][k]
        int kr = t >> 4, n4 = t & 15;
        float4 v = *(const float4*)&B[(size_t)(kc+kr)*ldb + j0 + n4*4];
        Bs[(n4*4+0)*72 + kr] = (short)f2bf(v.x);
        Bs[(n4*4+1)*72 + kr] = (short)f2bf(v.y);
        Bs[(n4*4+2)*72 + kr] = (short)f2bf(v.z);
        Bs[(n4*4+3)*72 + kr] = (short)f2bf(v.w);
      }
      __syncthreads();
      #pragma unroll
      for (int ks = 0; ks < 2; ++ks) {
        short8 a = *(const short8*)&As[(w*16+lane16)*72 + ks*32 + quad*8];
        #pragma unroll
        for (int nt = 0; nt < 4; ++nt) {
          short8 b8 = *(const short8*)&Bs[(nt*16+lane16)*72 + ks*32 + quad*8];
          acc[nt] = __builtin_amdgcn_mfma_f32_16x16x32_bf16(a, b8, acc[nt], 0, 0, 0);
        }
      }
      __syncthreads();
    }
    #pragma unroll
    for (int nt = 0; nt < 4; ++nt)
      #pragma unroll
      for (int r = 0; r < 4; ++r)
        C[(size_t)(i0 + w*16 + quad*4 + r)*ldc + j0 + nt*16 + lane16] = f2bf(acc[nt][r]);
  } else {                                  // ---- btmp / b12 ----
    int vb = blk - 591;
    int w = tid >> 6, l = tid & 63;
    if (vb < 512) {
      int o = vb*4 + w;
      float s = 0.f;
      for (int h = l; h < 512; h += 64) s += Wox2[(size_t)o*512 + h] * box1[h];
      for (int off = 32; off; off >>= 1) s += __shfl_down(s, off, 64);
      if (l == 0) ws[OFF_BTMP + o] = s + box2[o];
    } else {
      int o = (vb - 512)*4 + w;
      float s = 0.f;
      for (int h = l; h < 512; h += 64) s += Wo2[(size_t)o*512 + h] * bo1[h];
      for (int off = 32; off; off >>= 1) s += __shfl_down(s, off, 64);
      if (l == 0) ws[OFF_B12 + o] = s + bo2[o];
    }
  }
}

// ---------------- kmain5: partial xl over k-quarter; 2-deep prefetch; xp via partials ----------------
// grid (256 batches, 4 quarters) x 512 thr -> 1024 blocks, 3 blocks/CU at (512,6)

#define LOADCH(fR, gR, ptr) do {                                                  \
    if (p4A < 12) { float4 v_ = *(const float4*)((ptr) + cA*49 + p4A*4);          \
      fR[0]=v_.x; fR[1]=v_.y; fR[2]=v_.z; fR[3]=v_.w; }                           \
    else fR[0] = (ptr)[cA*49 + 48];                                               \
    if (hasB) {                                                                   \
      if (p4B < 12) { float4 v_ = *(const float4*)((ptr) + cB*49 + p4B*4);        \
        gR[0]=v_.x; gR[1]=v_.y; gR[2]=v_.z; gR[3]=v_.w; }                         \
      else gR[0] = (ptr)[cB*49 + 48]; }                                           \
  } while(0)

#define STAGECH(fR, gR, bt, xp) do {                                              \
    if (p4A < 12) {                                                               \
      bt[(p4A*4+0)*72 + cA] = (short)f2bf(fR[0]);                                 \
      bt[(p4A*4+1)*72 + cA] = (short)f2bf(fR[1]);                                 \
      bt[(p4A*4+2)*72 + cA] = (short)f2bf(fR[2]);                                 \
      bt[(p4A*4+3)*72 + cA] = (short)f2bf(fR[3]);                                 \
      xp[tid] = fR[0]+fR[1]+fR[2]+fR[3];                                          \
    } else { bt[48*72 + cA] = (short)f2bf(fR[0]); xp[tid] = fR[0]; }              \
    if (hasB) {                                                                   \
      if (p4B < 12) {                                                             \
        bt[(p4B*4+0)*72 + cB] = (short)f2bf(gR[0]);                               \
        bt[(p4B*4+1)*72 + cB] = (short)f2bf(gR[1]);                               \
        bt[(p4B*4+2)*72 + cB] = (short)f2bf(gR[2]);                               \
        bt[(p4B*4+3)*72 + cB] = (short)f2bf(gR[3]);                               \
        xp[512 + tid] = gR[0]+gR[1]+gR[2]+gR[3];                                  \
      } else { bt[48*72 + cB] = (short)f2bf(gR[0]); xp[512 + tid] = gR[0]; }      \
    }                                                                             \
  } while(0)

__global__ __launch_bounds__(512, 6) void kmain5(const float* __restrict__ x,
                                                 const short* __restrict__ w12bf,
                                                 short* __restrict__ xpbf,
                                                 float* __restrict__ part)
{
  __shared__ alignas(16) short Bt[2][64*72];
  __shared__ alignas(16) float xpp[2][832];
  int b = blockIdx.x, q = blockIdx.y, tid = threadIdx.x;
  int w = tid >> 6, l = tid & 63;
  int quad = l >> 4, lane16 = l & 15;
  const float* xb = x + ((size_t)b*2048 + q*512)*49;

  // staging tasks: 13 p-groups x 64 c = 832; thread t does tasks t and t+512
  int p4A = tid % 13, cA = tid / 13;
  int tB = tid + 512;
  int p4B = tB % 13, cB = tB / 13;
  bool hasB = (tid < 320);

  // 2-deep prefetch register double-buffer
  float f0[4], g0[4], f1[4], g1[4];
  LOADCH(f0, g0, xb);                 // chunk 0
  LOADCH(f1, g1, xb + 64*49);         // chunk 1

  f32x4 acc[4];
  #pragma unroll
  for (int i = 0; i < 4; ++i) acc[i] = (f32x4)(0.f);

  #pragma unroll
  for (int kci = 0; kci < 8; ++kci) {
    short* bt = Bt[kci & 1];
    float* xp = xpp[kci & 1];
    if ((kci & 1) == 0) { STAGECH(f0, g0, bt, xp); }
    else                { STAGECH(f1, g1, bt, xp); }
    __syncthreads();
    if (kci < 6) {                     // issue chunk kci+2 into the regs just consumed
      const float* xc = xb + (size_t)(kci+2)*64*49;
      if ((kci & 1) == 0) { LOADCH(f0, g0, xc); }
      else                { LOADCH(f1, g1, xc); }
    }
    // A frags from global (L2-resident); wave w owns o rows [w*16, w*16+16)
    const short* wr = w12bf + (size_t)(w*16 + lane16)*2048 + q*512 + kci*64 + quad*8;
    short8 a0 = *(const short8*)(wr);
    short8 a1 = *(const short8*)(wr + 32);
    #pragma unroll
    for (int ni = 0; ni < 4; ++ni) {
      const short* br = bt + (ni*16 + lane16)*72 + quad*8;
      short8 b0 = *(const short8*)(br);
      short8 b1 = *(const short8*)(br + 32);
      acc[ni] = __builtin_amdgcn_mfma_f32_16x16x32_bf16(a0, b0, acc[ni], 0, 0, 0);
      acc[ni] = __builtin_amdgcn_mfma_f32_16x16x32_bf16(a1, b1, acc[ni], 0, 0, 0);
    }
    if (tid < 64) {                    // xp reduce: 13 partials per channel
      float s = 0.f;
      #pragma unroll
      for (int j = 0; j < 13; ++j) s += xp[tid*13 + j];
      xpbf[(size_t)b*2048 + q*512 + kci*64 + tid] = (short)f2bf(s * (1.f/49.f));
    }
  }
  float* po = part + ((size_t)q*256 + b)*6656;   // [q][b][o][52]
  #pragma unroll
  for (int ni = 0; ni < 4; ++ni) {
    int p = ni*16 + lane16;
    if (p < 49) {
      #pragma unroll
      for (int r = 0; r < 4; ++r) {
        int o = w*16 + quad*4 + r;
        po[o*52 + p] = acc[ni][r];
      }
    }
  }
}

// ---------------- kwcf: Wc GEMM + bc + kfeat, one launch ----------------
__global__ __launch_bounds__(256) void kwcf(const float* __restrict__ Wb,
                                            const float* __restrict__ bb,
                                            const short* __restrict__ xpbf,
                                            float* __restrict__ featp,
                                            float* __restrict__ ws)
{
  __shared__ alignas(16) short As[64*72];
  __shared__ alignas(16) short Bs[64*72];
  int blk = blockIdx.x, tid = threadIdx.x;
  if (blk < 64) {                            // Wc += WBBF @ T1BF (split-K atomic)
    const short* wbbf = (const short*)(ws+OFF_WBBF);
    const short* t1s  = (const short*)(ws+OFF_T1BF);
    int i0 = (blk & 3)*64, j0 = ((blk >> 2) & 1)*64, kc0 = (blk >> 3)*256;
    int w = tid >> 6, l = tid & 63, quad = l >> 4, lane16 = l & 15;
    f32x4 acc[4];
    #pragma unroll
    for (int i = 0; i < 4; ++i) acc[i] = (f32x4)(0.f);
    for (int kc = kc0; kc < kc0+256; kc += 64) {
      for (int t = tid; t < 512; t += 256) {
        int r = t >> 3, c8 = t & 7;
        *(short8*)&As[r*72 + c8*8] = *(const short8*)&wbbf[(size_t)(i0+r)*2048 + kc + c8*8];
      }
      for (int t = tid; t < 1024; t += 256) {
        int kr = t >> 4, n4 = t & 15;
        s16x4 v = *(const s16x4*)&t1s[(size_t)(kc+kr)*128 + j0 + n4*4];
        Bs[(n4*4+0)*72 + kr] = v[0];
        Bs[(n4*4+1)*72 + kr] = v[1];
        Bs[(n4*4+2)*72 + kr] = v[2];
        Bs[(n4*4+3)*72 + kr] = v[3];
      }
      __syncthreads();
      #pragma unroll
      for (int ks = 0; ks < 2; ++ks) {
        short8 a = *(const short8*)&As[(w*16+lane16)*72 + ks*32 + quad*8];
        #pragma unroll
        for (int nt = 0; nt < 4; ++nt) {
          short8 b8 = *(const short8*)&Bs[(nt*16+lane16)*72 + ks*32 + quad*8];
          acc[nt] = __builtin_amdgcn_mfma_f32_16x16x32_bf16(a, b8, acc[nt], 0, 0, 0);
        }
      }
      __syncthreads();
    }
    #pragma unroll
    for (int nt = 0; nt < 4; ++nt)
      #pragma unroll
      for (int r = 0; r < 4; ++r)
        atomicAdd(&ws[OFF_WC + (size_t)(i0 + w*16 + quad*4 + r)*128 + j0 + nt*16 + lane16], acc[nt][r]);
  } else if (blk < 128) {                    // bc = Wb@btmp + bb
    int j = (blk-64)*4 + (tid >> 6), l = tid & 63;
    float s = 0.f;
    for (int c = l; c < 2048; c += 64) s += Wb[(size_t)j*2048 + c] * ws[OFF_BTMP + c];
    for (int off = 32; off; off >>= 1) s += __shfl_down(s, off, 64);
    if (l == 0) ws[OFF_BC + j] = s + bb[j];
  } else {                                   // featp += XPBF @ WBBF^T
    const short* wbbf = (const short*)(ws+OFF_WBBF);
    int idx = blk - 128;                     // 128 tiles: 4 x 4 x 8
    int i0 = (idx & 3)*64, j0 = ((idx >> 2) & 3)*64, kc0 = (idx >> 4)*256;
    int w = tid >> 6, l = tid & 63, quad = l >> 4, lane16 = l & 15;
    f32x4 acc[4];
    #pragma unroll
    for (int i = 0; i < 4; ++i) acc[i] = (f32x4)(0.f);
    for (int kc = kc0; kc < kc0+256; kc += 32) {
      short8 a = *(const short8*)&xpbf[(size_t)(i0 + w*16 + lane16)*2048 + kc + quad*8];
      #pragma unroll
      for (int nt = 0; nt < 4; ++nt) {
        short8 b8 = *(const short8*)&wbbf[(size_t)(j0 + nt*16 + lane16)*2048 + kc + quad*8];
        acc[nt] = __builtin_amdgcn_mfma_f32_16x16x32_bf16(a, b8, acc[nt], 0, 0, 0);
      }
    }
    #pragma unroll
    for (int nt = 0; nt < 4; ++nt)
      #pragma unroll
      for (int r = 0; r < 4; ++r)
        atomicAdd(&featp[(size_t)(i0 + w*16 + quad*4 + r)*256 + j0 + nt*16 + lane16], acc[nt][r]);
  }
}

// ---------------- kpr: pre_output + softmax + 64 PageRank iters (4-way split) ----------------
__global__ __launch_bounds__(384) void kpr(const float* __restrict__ featp,
                                           const float* __restrict__ Wfc,
                                           const float* __restrict__ wpr,
                                           float* __restrict__ preo,
                                           float* __restrict__ vy)
{
  __shared__ alignas(16) float fpr[256];
  __shared__ alignas(16) float po[68];
  __shared__ alignas(16) float vsA[88];
  __shared__ alignas(16) float vsB[88];
  __shared__ alignas(16) float vis[88];
  __shared__ float rd[4];
  int b = blockIdx.x, tid = threadIdx.x;
  if (tid < 256) fpr[tid] = featp[b*256 + tid];
  __syncthreads();
  if (tid < 260) {                            // po: 65 rows x 4-lane split
    int row = tid >> 2, p = tid & 3;
    float s = 0.f;
    const float* wr = Wfc + row*256 + p*64;
    #pragma unroll
    for (int c = 0; c < 64; c += 4) {
      float4 w4 = *(const float4*)&wr[c];
      s += w4.x*fpr[p*64+c] + w4.y*fpr[p*64+c+1] + w4.z*fpr[p*64+c+2] + w4.w*fpr[p*64+c+3];
    }
    s += __shfl_xor(s, 1, 64);
    s += __shfl_xor(s, 2, 64);
    if (p == 0) { po[row] = s; preo[b*65 + row] = s; }
  }
  __syncthreads();
  if (tid < 64) {                             // softmax reduce
    float v = po[tid];
    if (tid == 0) v = fmaxf(v, po[64]);
    float mx = v;
    #pragma unroll
    for (int off = 32; off; off >>= 1) mx = fmaxf(mx, __shfl_down(mx, off, 64));
    mx = __shfl(mx, 0, 64);
    float e = expf(po[tid]-mx) + ((tid == 0) ? expf(po[64]-mx) : 0.f);
    float sm = e;
    #pragma unroll
    for (int off = 32; off; off >>= 1) sm += __shfl_down(sm, off, 64);
    if (tid == 0) { rd[0] = mx; rd[1] = 1.f/sm; }
  }
  __syncthreads();
  if (tid < 88) {
    float vin = (tid >= 22 && tid < 87) ? expf(po[tid-22]-rd[0])*rd[1] : 0.f;
    vis[tid] = vin;
    vsA[tid] = vin * 87.f;
    vsB[tid] = 0.f;
  }
  __syncthreads();
  float wrow[22];
  const int m4 = tid >> 2, pp = tid & 3;
  if (tid < 348) {                            // row m4, k-quarter pp
    float add = vis[m4] * 0.15f;              // = s_i*(0.15/87) with s_i=vinit*87
    #pragma unroll
    for (int jj = 0; jj < 22; ++jj) {
      int j = pp*22 + jj;
      wrow[jj] = (j < 87) ? (wpr[m4*87 + j] + add) : 0.f;
    }
  }
  for (int it = 0; it < 64; ++it) {
    const float* vc = (it & 1) ? vsB : vsA;
    float* vn = (it & 1) ? vsA : vsB;
    if (tid < 348) {
      float nv = 0.f;
      #pragma unroll
      for (int jj = 0; jj < 22; ++jj) nv += wrow[jj] * vc[pp*22 + jj];
      nv += __shfl_xor(nv, 1, 64);
      nv += __shfl_xor(nv, 2, 64);
      if (pp == 0) vn[m4] = nv;
    }
    __syncthreads();
  }
  if (tid < 64) {                             // L2 norm over vsA[0..86]
    float v = vsA[tid]*vsA[tid];
    if (tid < 23) v += vsA[64+tid]*vsA[64+tid];
    #pragma unroll
    for (int off = 32; off; off >>= 1) v += __shfl_down(v, off, 64);
    if (tid == 0) rd[2] = 1.f / fmaxf(sqrtf(v), 1e-12f);
  }
  __syncthreads();
  if (tid < 87) vy[b*87 + tid] = vis[tid] + vsA[tid]*rd[2];
}

// ---------------- knode: 4-way k-split over 256 blocks ----------------
__global__ __launch_bounds__(384) void knode(const float* __restrict__ Wg,
                                             const float* __restrict__ node_p,
                                             const float* __restrict__ vy,
                                             float* __restrict__ nt)
{
  int tid = threadIdx.x;
  if (tid >= 352) return;
  int out = blockIdx.x*88 + (tid >> 2);       // < 22528
  int par = out / 11264;
  int r = out % 11264;
  int o = r / 88, m = r % 88;
  int p = tid & 3;
  float s = 0.f;
  if (m < 87) {
    const float* vrow = vy + (size_t)(par*128)*87 + m;
    for (int k = p*32; k < p*32+32; ++k)
      s += Wg[o*256 + k] * node_p[k*87 + m] * vrow[k*87];
  }
  s += __shfl_xor(s, 1, 64);
  s += __shfl_xor(s, 2, 64);
  if (p == 0) nt[out] = s;
}

// ---------------- kgraph_all: MFMA graph chain + finale, all in LDS ----------------
__global__ __launch_bounds__(512) void kgraph_all(
    const float* __restrict__ part,  const float* __restrict__ b12,
    const short* __restrict__ wapbf, const float* __restrict__ b215,
    const short* __restrict__ wg2bf, const float* __restrict__ nt,
    const float* __restrict__ bg,    const short* __restrict__ enpbf,
    const float* __restrict__ Wsp,   const float* __restrict__ bsp,
    const float* __restrict__ Ws,    const float* __restrict__ wc,
    const float* __restrict__ bc,    const float* __restrict__ featp,
    const float* __restrict__ Wfc2,
    float* __restrict__ feat, float* __restrict__ out2, float* __restrict__ soft)
{
  extern __shared__ char smraw[];
  short* XT = (short*)smraw;             // [64][136]
  short* At = XT + 8704;                 // [224][72]
  short* M1 = At + 16128;                // [96][136]
  short* G  = M1 + 13056;                // [128][104]
  short* M2 = G  + 13312;                // [128][104]
  float* fb  = (float*)(M2 + 13312);
  float* wsm = fb;                       // 96
  float* tnb = fb + 96;                  // 96
  float* zs  = fb + 192;                 // 128
  float* m3s = fb + 320;                 // 128
  float* fs  = fb + 448;                 // 256
  float* o2s = fb + 704;                 // 72
  float* red = fb + 776;                 // 4

  int b = blockIdx.x, tid = threadIdx.x;
  int w = tid >> 6, l = tid & 63, quad = l >> 4, lane16 = l & 15;

  // stage XT[p][c] = bf16(sum of 4 quarter-partials + b12)
  const float* p0 = part + (size_t)b*6656;
  const float* p1 = p0 + (size_t)256*6656;
  const float* p2 = p1 + (size_t)256*6656;
  const float* p3 = p2 + (size_t)256*6656;
  for (int t = tid; t < 6656; t += 512) {
    int o = t / 52, p = t % 52;
    XT[p*136 + o] = (short)f2bf(p0[t] + p1[t] + p2[t] + p3[t] + b12[o]);
  }
  for (int t = tid; t < 1536; t += 512) {        // zero rows p=52..63
    int p = 52 + t/128, o = t % 128;
    XT[p*136 + o] = 0;
  }
  __syncthreads();

  // phase 1a: At[r][p] = Wap @ xl + b215   (M=224, N=64, K=128)
  for (int t = w; t < 56; t += 8) {
    int mt = t >> 2, n4 = t & 3;
    f32x4 acc = (f32x4)(0.f);
    #pragma unroll
    for (int ks = 0; ks < 4; ++ks) {
      short8 a  = *(const short8*)&wapbf[(size_t)(mt*16+lane16)*128 + ks*32 + quad*8];
      short8 b8 = *(const short8*)&XT[(n4*16+lane16)*136 + ks*32 + quad*8];
      acc = __builtin_amdgcn_mfma_f32_16x16x32_bf16(a, b8, acc, 0, 0, 0);
    }
    int p = n4*16 + lane16;
    #pragma unroll
    for (int r = 0; r < 4; ++r) {
      int rr = mt*16 + quad*4 + r;
      At[rr*72 + p] = (p < 49) ? (short)f2bf(acc[r] + b215[rr]) : (short)0;
    }
  }
  __syncthreads();

  // phase 1b: M1[m][d] = relu(a-rows @ ps-rows^T)   (M=96, N=128, K=64)
  for (int t = w; t < 48; t += 8) {
    int mt = t / 8, n4 = t % 8;
    f32x4 acc = (f32x4)(0.f);
    #pragma unroll
    for (int ks = 0; ks < 2; ++ks) {
      short8 a  = *(const short8*)&At[(128 + mt*16 + lane16)*72 + ks*32 + quad*8];
      short8 b8 = *(const short8*)&At[(n4*16+lane16)*72 + ks*32 + quad*8];
      acc = __builtin_amdgcn_mfma_f32_16x16x32_bf16(a, b8, acc, 0, 0, 0);
    }
    int d = n4*16 + lane16;
    #pragma unroll
    for (int r = 0; r < 4; ++r) {
      int m = mt*16 + quad*4 + r;
      M1[m*136 + d] = (short)f2bf(fmaxf(acc[r], 0.f));
    }
  }
  __syncthreads();

  // phase 2: G[o][m] = Wg2 @ m1 + nt + bg   (M=128, N=96, K=128)
  const float* ntb = nt + (size_t)(b & 1)*11264;
  for (int t = w; t < 48; t += 8) {
    int mt = t / 6, n4 = t % 6;
    f32x4 acc = (f32x4)(0.f);
    #pragma unroll
    for (int ks = 0; ks < 4; ++ks) {
      short8 a  = *(const short8*)&wg2bf[(size_t)(mt*16+lane16)*128 + ks*32 + quad*8];
      short8 b8 = *(const short8*)&M1[(n4*16+lane16)*136 + ks*32 + quad*8];
      acc = __builtin_amdgcn_mfma_f32_16x16x32_bf16(a, b8, acc, 0, 0, 0);
    }
    int m = n4*16 + lane16;
    #pragma unroll
    for (int r = 0; r < 4; ++r) {
      int o = mt*16 + quad*4 + r;
      float v = acc[r] + bg[o] + ((m < 88) ? ntb[o*88 + m] : 0.f);
      G[o*104 + m] = (short)f2bf(v);
    }
  }
  __syncthreads();

  // phase 3: M2[c][n] = relu(G @ enp)   (M=128, N=96, K=96; enp symmetric)
  for (int t = w; t < 48; t += 8) {
    int mt = t / 6, n4 = t % 6;
    f32x4 acc = (f32x4)(0.f);
    #pragma unroll
    for (int ks = 0; ks < 3; ++ks) {
      short8 a  = *(const short8*)&G[(mt*16+lane16)*104 + ks*32 + quad*8];
      short8 b8 = *(const short8*)&enpbf[(size_t)(n4*16+lane16)*96 + ks*32 + quad*8];
      acc = __builtin_amdgcn_mfma_f32_16x16x32_bf16(a, b8, acc, 0, 0, 0);
    }
    int n = n4*16 + lane16;
    #pragma unroll
    for (int r = 0; r < 4; ++r) {
      int c = mt*16 + quad*4 + r;
      M2[c*104 + n] = (short)f2bf(fmaxf(acc[r], 0.f));
    }
  }
  __syncthreads();

  // phase 4: node softmax + m3 (serial chains split 4-way across lanes)
  if (tid < 348) {                            // tnb[m] = Ws . M2[:,m]
    int m = tid >> 2, p = tid & 3;
    float s = 0.f;
    for (int c = p*32; c < p*32+32; ++c)
      s += Ws[c] * bf2f((unsigned short)M2[c*104 + m]);
    s += __shfl_xor(s, 1, 64);
    s += __shfl_xor(s, 2, 64);
    if (p == 0) tnb[m] = s;
  }
  __syncthreads();
  if (tid < 64) {
    float v = tnb[tid];
    if (tid < 23) v = fmaxf(v, tnb[64+tid]);
    float mx = v;
    #pragma unroll
    for (int off = 32; off; off >>= 1) mx = fmaxf(mx, __shfl_down(mx, off, 64));
    mx = __shfl(mx, 0, 64);
    float e0 = expf(tnb[tid]-mx);
    float e1 = (tid < 23) ? expf(tnb[64+tid]-mx) : 0.f;
    float sm = e0 + e1;
    #pragma unroll
    for (int off = 32; off; off >>= 1) sm += __shfl_down(sm, off, 64);
    sm = __shfl(sm, 0, 64);
    float inv = 1.f/sm;
    wsm[tid] = e0*inv;
    if (tid < 23) wsm[64+tid] = e1*inv;
  }
  __syncthreads();
  {                                           // zs[c] = M2[c,:] . wsm
    int c = tid >> 2, p = tid & 3;
    float s = 0.f;
    for (int mm = p*22; mm < p*22+22 && mm < 87; ++mm)
      s += bf2f((unsigned short)M2[c*104 + mm]) * wsm[mm];
    s += __shfl_xor(s, 1, 64);
    s += __shfl_xor(s, 2, 64);
    if (p == 0) zs[c] = s;
  }
  __syncthreads();
  {                                           // m3s[d] = relu(Wsp[d,:] . zs + bsp)
    int d = tid >> 2, p = tid & 3;
    float s = 0.f;
    for (int c = p*32; c < p*32+32; ++c) s += Wsp[d*128 + c] * zs[c];
    s += __shfl_xor(s, 1, 64);
    s += __shfl_xor(s, 2, 64);
    if (p == 0) m3s[d] = fmaxf(s + bsp[d], 0.f);
  }
  __syncthreads();

  // phase 5: features / outputs2 / softmax
  if (tid < 256) {
    float s = 0.f;
    #pragma unroll 4
    for (int d4 = 0; d4 < 32; ++d4) {
      float4 w4 = *(const float4*)&wc[tid*128 + d4*4];
      s += w4.x*m3s[d4*4] + w4.y*m3s[d4*4+1] + w4.z*m3s[d4*4+2] + w4.w*m3s[d4*4+3];
    }
    float f = featp[b*256 + tid] + bc[tid] + s;
    fs[tid] = f;
    feat[b*256 + tid] = f;
  }
  __syncthreads();
  if (tid < 260) {                            // out2: 65 rows x 4-lane split
    int row = tid >> 2, p = tid & 3;
    float s = 0.f;
    for (int c = p*64; c < p*64+64; c += 4) {
      float4 w4 = *(const float4*)&Wfc2[row*256 + c];
      s += w4.x*fs[c] + w4.y*fs[c+1] + w4.z*fs[c+2] + w4.w*fs[c+3];
    }
    s += __shfl_xor(s, 1, 64);
    s += __shfl_xor(s, 2, 64);
    if (p == 0) { out2[b*65 + row] = s; o2s[row] = s; }
  }
  __syncthreads();
  if (tid < 64) {
    float v = o2s[tid];
    if (tid == 0) v = fmaxf(v, o2s[64]);
    float mx = v;
    #pragma unroll
    for (int off = 32; off; off >>= 1) mx = fmaxf(mx, __shfl_down(mx, off, 64));
    mx = __shfl(mx, 0, 64);
    float e = expf(o2s[tid]-mx) + ((tid == 0) ? expf(o2s[64]-mx) : 0.f);
    float sm = e;
    #pragma unroll
    for (int off = 32; off; off >>= 1) sm += __shfl_down(sm, off, 64);
    if (tid == 0) { red[0] = mx; red[1] = 1.f/sm; }
  }
  __syncthreads();
  if (tid < 65) soft[b*65 + tid] = expf(o2s[tid]-red[0]) * red[1];
}

// ---------------- launch ----------------
extern "C" void kernel_launch(void* const* d_in, const int* in_sizes, int n_in,
                              void* d_out, int out_size, void* d_ws, size_t ws_size,
                              hipStream_t stream)
{
  (void)in_sizes; (void)n_in; (void)out_size; (void)ws_size;
  const float* x      = (const float*)d_in[0];
  const float* Wb     = (const float*)d_in[1];
  const float* bb     = (const float*)d_in[2];
  const float* Wfc    = (const float*)d_in[3];
  const float* Wfc2   = (const float*)d_in[4];
  const float* Wo1    = (const float*)d_in[5];
  const float* bo1    = (const float*)d_in[6];
  const float* Wo2    = (const float*)d_in[7];
  const float* bo2    = (const float*)d_in[8];
  const float* Wa     = (const float*)d_in[9];
  const float* ba     = (const float*)d_in[10];
  const float* Wps    = (const float*)d_in[11];
  const float* bps    = (const float*)d_in[12];
  const float* node_p = (const float*)d_in[13];
  const float* Wg     = (const float*)d_in[14];
  const float* bg     = (const float*)d_in[15];
  const float* Wsp    = (const float*)d_in[16];
  const float* bsp    = (const float*)d_in[17];
  const float* Ws     = (const float*)d_in[18];
  const float* Wox1   = (const float*)d_in[20];
  const float* box1   = (const float*)d_in[21];
  const float* Wox2   = (const float*)d_in[22];
  const float* box2   = (const float*)d_in[23];
  const float* edge   = (const float*)d_in[24];

  float* ws   = (float*)d_ws;
  float* out  = (float*)d_out;
  float* feat  = out;            // (256,256)
  float* out2  = out + 65536;    // (256,65)
  float* soft  = out + 82176;    // (256,65)
  float* preo  = out + 98816;    // (256,65)
  float* featp = out + 115456;   // (256,256)

  ksetup_all<<<1135, 256, 0, stream>>>(Wb, bb, Wa, ba, Wps, bps, Wg, edge,
                                       Wo2, Wo1, Wox2, Wox1, box1, box2, bo1, bo2,
                                       ws, featp);
  kmain5<<<dim3(256,4), 512, 0, stream>>>(x, (const short*)(ws + OFF_W12BF),
                                          (short*)(ws + OFF_XPBF), ws + OFF_PART);
  kwcf<<<256, 256, 0, stream>>>(Wb, bb, (const short*)(ws + OFF_XPBF), featp, ws);
  kpr<<<256, 384, 0, stream>>>(featp, Wfc, ws + OFF_WPR, preo, ws + OFF_VY);
  knode<<<256, 384, 0, stream>>>(Wg, node_p, ws + OFF_VY, ws + OFF_NT);
  kgraph_all<<<256, 512, 132144, stream>>>(ws + OFF_PART, ws + OFF_B12,
                                           (const short*)(ws + OFF_WAPBF),
                                           ws + OFF_B215,
                                           (const short*)(ws + OFF_WG2BF),
                                           ws + OFF_NT, bg,
                                           (const short*)(ws + OFF_ENPBF),
                                           Wsp, bsp, Ws,
                                           ws + OFF_WC, ws + OFF_BC, featp, Wfc2,
                                           feat, out2, soft);
}

// Round 7
// 315.028 us; speedup vs baseline: 1.1084x; 1.1084x over previous
//
#include <hip/hip_runtime.h>
#include <cmath>

// M=87, CLS=65, K=128, DL=DC=128, DO=2048, BD=256, B=256, HW=49

typedef __attribute__((ext_vector_type(8))) short short8;
typedef __attribute__((ext_vector_type(4))) short s16x4;
typedef __attribute__((ext_vector_type(4))) float f32x4;

// ---------------- workspace layout (float offsets) ----------------
constexpr size_t OFF_W12BF = 0;          // [128][2048] bf16
constexpr size_t OFF_T1BF  = 131072;     // [2048][128] bf16 (Wox2@Wox1)
constexpr size_t OFF_WBBF  = 262144;     // [256][2048] bf16
constexpr size_t OFF_XPBF  = 524288;     // [256][2048] bf16
constexpr size_t OFF_WAPBF = 786432;     // [224][128] bf16 (Wps;Wa;0)
constexpr size_t OFF_WG2BF = 800768;     // [128][128] bf16
constexpr size_t OFF_ENPBF = 808960;     // [96][96] bf16 edge_norm (symmetric)
constexpr size_t OFF_B215  = 813568;     // 224 f
constexpr size_t OFF_B12   = 813792;     // 128 f
constexpr size_t OFF_WPR   = 813920;     // 87x87 f
constexpr size_t OFF_BTMP  = 821496;     // 2048 f
constexpr size_t OFF_WC    = 823544;     // [256][128] f (atomic accum)
constexpr size_t OFF_BC    = 856312;     // 256 f
constexpr size_t OFF_VY    = 856568;     // 256x87 f
constexpr size_t OFF_NT    = 878848;     // [2][128][88] f
constexpr size_t OFF_PART  = 901376;     // [4][256][128][52] f partial xl

__device__ __forceinline__ unsigned short f2bf(float f) {
  unsigned u = __builtin_bit_cast(unsigned, f);
  u += 0x7fffu + ((u >> 16) & 1u);
  return (unsigned short)(u >> 16);
}
__device__ __forceinline__ float bf2f(unsigned short s) {
  return __builtin_bit_cast(float, ((unsigned)s) << 16);
}

// ---------------- ksetup_all: casts/inits + weight GEMMs + bias vecs ----------------
// block map: [0,256) WBBF8 | [256,320) featp4 | [320,352) Wc0 | [352,380) WAP4 |
// [380,396) WG2_4 | [396,432) ENP | [432,462) WPR | 462 b215 | [463,591) GEMM | [591,1135) btmp/b12
__global__ __launch_bounds__(256) void ksetup_all(
    const float* __restrict__ Wb,  const float* __restrict__ bb,
    const float* __restrict__ Wa,  const float* __restrict__ ba,
    const float* __restrict__ Wps, const float* __restrict__ bps,
    const float* __restrict__ Wg,  const float* __restrict__ edge,
    const float* __restrict__ Wo2, const float* __restrict__ Wo1,
    const float* __restrict__ Wox2,const float* __restrict__ Wox1,
    const float* __restrict__ box1,const float* __restrict__ box2,
    const float* __restrict__ bo1, const float* __restrict__ bo2,
    float* __restrict__ ws, float* __restrict__ featp)
{
  __shared__ alignas(16) short As[64*72];
  __shared__ alignas(16) short Bs[64*72];
  int blk = blockIdx.x, tid = threadIdx.x;
  if (blk < 256) {                         // WBBF cast, 8 elems/thread
    int base = (blk*256 + tid)*8;
    float4 v0 = *(const float4*)&Wb[base];
    float4 v1 = *(const float4*)&Wb[base+4];
    short8 sv;
    sv[0]=(short)f2bf(v0.x); sv[1]=(short)f2bf(v0.y); sv[2]=(short)f2bf(v0.z); sv[3]=(short)f2bf(v0.w);
    sv[4]=(short)f2bf(v1.x); sv[5]=(short)f2bf(v1.y); sv[6]=(short)f2bf(v1.z); sv[7]=(short)f2bf(v1.w);
    *(short8*)&((unsigned short*)(ws+OFF_WBBF))[base] = sv;
  } else if (blk < 320) {                  // featp init = bb, 4/thread
    int idx4 = ((blk-256)*256 + tid)*4;
    float4 bv = *(const float4*)&bb[idx4 & 255];
    *(float4*)&featp[idx4] = bv;
  } else if (blk < 352) {                  // zero Wc, 4/thread
    int idx4 = ((blk-320)*256 + tid)*4;
    float4 z; z.x=z.y=z.z=z.w=0.f;
    *(float4*)&ws[OFF_WC + idx4] = z;
  } else if (blk < 380) {                  // WAPBF [r=224][c=128], 4/thread
    int idx4 = ((blk-352)*256 + tid)*4;    // < 28672
    int r = idx4 >> 7, c = idx4 & 127;
    float4 v;
    if (r < 128)      v = *(const float4*)&Wps[r*128 + c];
    else if (r < 215) v = *(const float4*)&Wa[(r-128)*128 + c];
    else              { v.x=v.y=v.z=v.w=0.f; }
    s16x4 sv; sv[0]=(short)f2bf(v.x); sv[1]=(short)f2bf(v.y); sv[2]=(short)f2bf(v.z); sv[3]=(short)f2bf(v.w);
    *(s16x4*)&((unsigned short*)(ws+OFF_WAPBF))[idx4] = sv;
  } else if (blk < 396) {                  // WG2BF [o][d], 4/thread
    int idx4 = ((blk-380)*256 + tid)*4;    // < 16384
    int o = idx4 >> 7, d = idx4 & 127;
    float4 v = *(const float4*)&Wg[o*256 + 128 + d];
    s16x4 sv; sv[0]=(short)f2bf(v.x); sv[1]=(short)f2bf(v.y); sv[2]=(short)f2bf(v.z); sv[3]=(short)f2bf(v.w);
    *(s16x4*)&((unsigned short*)(ws+OFF_WG2BF))[idx4] = sv;
  } else if (blk < 432) {                  // ENPBF [96][96], zero-padded
    int idx = (blk-396)*256 + tid;         // < 9216
    int m = idx / 96, n = idx % 96;
    float v = 0.f;
    if (m < 87 && n < 87) {
      float sm = 0.f, sn = 0.f;
      for (int k = 0; k < 87; ++k) { sm += edge[k*87+m]; sn += edge[k*87+n]; }
      v = edge[m*87+n] / sqrtf(sm*sn);
    }
    ((unsigned short*)(ws+OFF_ENPBF))[idx] = f2bf(v);
  } else if (blk < 462) {                  // WPR fp32
    int idx = (blk-432)*256 + tid;
    if (idx < 87*87) {
      int j = idx % 87;
      float rs = 0.f;
      for (int k = 0; k < 87; ++k) rs += edge[j*87+k];
      ws[OFF_WPR + idx] = 0.85f * edge[idx] / rs;
    }
  } else if (blk == 462) {                 // b215 (pad 224)
    if (tid < 224) {
      float v = (tid < 128) ? bps[tid] : (tid < 215 ? ba[tid-128] : 0.f);
      ws[OFF_B215 + tid] = v;
    }
  } else if (blk < 591) {                  // ---- W12 / T1 MFMA tiles, 1-deep reg prefetch ----
    int gb = blk - 463;
    const float *A, *B; unsigned short* C; int lda, ldb, ldc, i0, j0;
    if (gb < 64) {   // W12 [128][2048] = Wo2@Wo1
      A = Wo2; B = Wo1; C = (unsigned short*)(ws+OFF_W12BF);
      lda = 512; ldb = 2048; ldc = 2048;
      i0 = (gb & 1)*64; j0 = (gb >> 1)*64;
    } else {         // T1 [2048][128] = Wox2@Wox1
      int b2 = gb - 64;
      A = Wox2; B = Wox1; C = (unsigned short*)(ws+OFF_T1BF);
      lda = 512; ldb = 128; ldc = 128;
      i0 = (b2 >> 1)*64; j0 = (b2 & 1)*64;
    }
    int w = tid >> 6, l = tid & 63, quad = l >> 4, lane16 = l & 15;
    // staging task split: rounds j=0..3, task t = tid + j*256; r=t>>4, c4=t&15
    int rT[4], c4[4];
    #pragma unroll
    for (int j = 0; j < 4; ++j) { int t = tid + j*256; rT[j] = t >> 4; c4[j] = t & 15; }
    float4 av[4], bv[4];
    #pragma unroll
    for (int j = 0; j < 4; ++j) {           // prefetch chunk kc=0
      av[j] = *(const float4*)&A[(size_t)(i0+rT[j])*lda + c4[j]*4];
      bv[j] = *(const float4*)&B[(size_t)rT[j]*ldb + j0 + c4[j]*4];
    }
    f32x4 acc[4];
    #pragma unroll
    for (int i = 0; i < 4; ++i) acc[i] = (f32x4)(0.f);
    for (int kc = 0; kc < 512; kc += 64) {  // rolled loop: prefetch cannot sink past backedge
      #pragma unroll
      for (int j = 0; j < 4; ++j) {         // A stage [m][k] from regs
        s16x4 sv; sv[0]=(short)f2bf(av[j].x); sv[1]=(short)f2bf(av[j].y);
        sv[2]=(short)f2bf(av[j].z); sv[3]=(short)f2bf(av[j].w);
        *(s16x4*)&As[rT[j]*72 + c4[j]*4] = sv;
        Bs[(c4[j]*4+0)*72 + rT[j]] = (short)f2bf(bv[j].x);   // B transpose-stage -> [n][k]
        Bs[(c4[j]*4+1)*72 + rT[j]] = (short)f2bf(bv[j].y);
        Bs[(c4[j]*4+2)*72 + rT[j]] = (short)f2bf(bv[j].z);
        Bs[(c4[j]*4+3)*72 + rT[j]] = (short)f2bf(bv[j].w);
      }
      __syncthreads();
      if (kc < 448) {                       // prefetch next chunk into regs
        #pragma unroll
        for (int j = 0; j < 4; ++j) {
          av[j] = *(const float4*)&A[(size_t)(i0+rT[j])*lda + (kc+64) + c4[j]*4];
          bv[j] = *(const float4*)&B[(size_t)(kc+64+rT[j])*ldb + j0 + c4[j]*4];
        }
      }
      #pragma unroll
      for (int ks = 0; ks < 2; ++ks) {
        short8 a = *(const short8*)&As[(w*16+lane16)*72 + ks*32 + quad*8];
        #pragma unroll
        for (int nt = 0; nt < 4; ++nt) {
          short8 b8 = *(const short8*)&Bs[(nt*16+lane16)*72 + ks*32 + quad*8];
          acc[nt] = __builtin_amdgcn_mfma_f32_16x16x32_bf16(a, b8, acc[nt], 0, 0, 0);
        }
      }
      __syncthreads();
    }
    #pragma unroll
    for (int nt = 0; nt < 4; ++nt)
      #pragma unroll
      for (int r = 0; r < 4; ++r)
        C[(size_t)(i0 + w*16 + quad*4 + r)*ldc + j0 + nt*16 + lane16] = f2bf(acc[nt][r]);
  } else {                                  // ---- btmp / b12 ----
    int vb = blk - 591;
    int w = tid >> 6, l = tid & 63;
    if (vb < 512) {
      int o = vb*4 + w;
      float s = 0.f;
      for (int h = l; h < 512; h += 64) s += Wox2[(size_t)o*512 + h] * box1[h];
      for (int off = 32; off; off >>= 1) s += __shfl_down(s, off, 64);
      if (l == 0) ws[OFF_BTMP + o] = s + box2[o];
    } else {
      int o = (vb - 512)*4 + w;
      float s = 0.f;
      for (int h = l; h < 512; h += 64) s += Wo2[(size_t)o*512 + h] * bo1[h];
      for (int off = 32; off; off >>= 1) s += __shfl_down(s, off, 64);
      if (l == 0) ws[OFF_B12 + o] = s + bo2[o];
    }
  }
}

// ---------------- kmain5: partial xl over k-quarter; xp(bf16) fused ----------------
// EXACT R2 (331 us build) version: rolled loop, 1-deep reg prefetch, serial xp.
__global__ __launch_bounds__(512, 6) void kmain5(const float* __restrict__ x,
                                                 const short* __restrict__ w12bf,
                                                 short* __restrict__ xpbf,
                                                 float* __restrict__ part)
{
  __shared__ alignas(16) short Bt[2][64*72];
  int b = blockIdx.x, q = blockIdx.y, tid = threadIdx.x;
  int w = tid >> 6, l = tid & 63;
  int quad = l >> 4, lane16 = l & 15;
  const float* xb = x + ((size_t)b*2048 + q*512)*49;

  // staging tasks: 13 p-groups x 64 c = 832; thread t does tasks t and t+512
  int p4A = tid % 13, cA = tid / 13;
  int tB = tid + 512;
  int p4B = tB % 13, cB = tB / 13;
  bool hasB = (tid < 320);

  float fA[4], fB[4];
  {
    if (p4A < 12) {
      float4 v = *(const float4*)(xb + cA*49 + p4A*4);
      fA[0]=v.x; fA[1]=v.y; fA[2]=v.z; fA[3]=v.w;
    } else fA[0] = xb[cA*49 + 48];
    if (hasB) {
      if (p4B < 12) {
        float4 v = *(const float4*)(xb + cB*49 + p4B*4);
        fB[0]=v.x; fB[1]=v.y; fB[2]=v.z; fB[3]=v.w;
      } else fB[0] = xb[cB*49 + 48];
    }
  }

  f32x4 acc[4];
  #pragma unroll
  for (int i = 0; i < 4; ++i) acc[i] = (f32x4)(0.f);

  for (int kci = 0; kci < 8; ++kci) {
    short* bt = Bt[kci & 1];
    if (p4A < 12) {
      #pragma unroll
      for (int i = 0; i < 4; ++i) bt[(p4A*4+i)*72 + cA] = (short)f2bf(fA[i]);
    } else bt[48*72 + cA] = (short)f2bf(fA[0]);
    if (hasB) {
      if (p4B < 12) {
        #pragma unroll
        for (int i = 0; i < 4; ++i) bt[(p4B*4+i)*72 + cB] = (short)f2bf(fB[i]);
      } else bt[48*72 + cB] = (short)f2bf(fB[0]);
    }
    __syncthreads();
    if (kci < 7) {                           // prefetch next chunk
      const float* xc = xb + (size_t)(kci+1)*64*49;
      if (p4A < 12) {
        float4 v = *(const float4*)(xc + cA*49 + p4A*4);
        fA[0]=v.x; fA[1]=v.y; fA[2]=v.z; fA[3]=v.w;
      } else fA[0] = xc[cA*49 + 48];
      if (hasB) {
        if (p4B < 12) {
          float4 v = *(const float4*)(xc + cB*49 + p4B*4);
          fB[0]=v.x; fB[1]=v.y; fB[2]=v.z; fB[3]=v.w;
        } else fB[0] = xc[cB*49 + 48];
      }
    }
    // A frags from global (L2-resident); wave w owns o rows [w*16, w*16+16)
    const short* wr = w12bf + (size_t)(w*16 + lane16)*2048 + q*512 + kci*64 + quad*8;
    short8 a0 = *(const short8*)(wr);
    short8 a1 = *(const short8*)(wr + 32);
    #pragma unroll
    for (int ni = 0; ni < 4; ++ni) {
      const short* br = bt + (ni*16 + lane16)*72 + quad*8;
      short8 b0 = *(const short8*)(br);
      short8 b1 = *(const short8*)(br + 32);
      acc[ni] = __builtin_amdgcn_mfma_f32_16x16x32_bf16(a0, b0, acc[ni], 0, 0, 0);
      acc[ni] = __builtin_amdgcn_mfma_f32_16x16x32_bf16(a1, b1, acc[ni], 0, 0, 0);
    }
    if (tid < 64) {                          // fused xp for this chunk's c-range
      float s = 0.f;
      for (int p = 0; p < 49; ++p)
        s += bf2f((unsigned short)bt[p*72 + tid]);
      xpbf[(size_t)b*2048 + q*512 + kci*64 + tid] = (short)f2bf(s * (1.f/49.f));
    }
  }
  float* po = part + ((size_t)q*256 + b)*6656;   // [q][b][o][52]
  #pragma unroll
  for (int ni = 0; ni < 4; ++ni) {
    int p = ni*16 + lane16;
    if (p < 49) {
      #pragma unroll
      for (int r = 0; r < 4; ++r) {
        int o = w*16 + quad*4 + r;
        po[o*52 + p] = acc[ni][r];
      }
    }
  }
}

// ---------------- kwcf: Wc GEMM + bc + kfeat, one launch ----------------
__global__ __launch_bounds__(256) void kwcf(const float* __restrict__ Wb,
                                            const float* __restrict__ bb,
                                            const short* __restrict__ xpbf,
                                            float* __restrict__ featp,
                                            float* __restrict__ ws)
{
  __shared__ alignas(16) short As[64*72];
  __shared__ alignas(16) short Bs[64*72];
  int blk = blockIdx.x, tid = threadIdx.x;
  if (blk < 64) {                            // Wc += WBBF @ T1BF (split-K atomic)
    const short* wbbf = (const short*)(ws+OFF_WBBF);
    const short* t1s  = (const short*)(ws+OFF_T1BF);
    int i0 = (blk & 3)*64, j0 = ((blk >> 2) & 1)*64, kc0 = (blk >> 3)*256;
    int w = tid >> 6, l = tid & 63, quad = l >> 4, lane16 = l & 15;
    f32x4 acc[4];
    #pragma unroll
    for (int i = 0; i < 4; ++i) acc[i] = (f32x4)(0.f);
    for (int kc = kc0; kc < kc0+256; kc += 64) {
      for (int t = tid; t < 512; t += 256) {
        int r = t >> 3, c8 = t & 7;
        *(short8*)&As[r*72 + c8*8] = *(const short8*)&wbbf[(size_t)(i0+r)*2048 + kc + c8*8];
      }
      for (int t = tid; t < 1024; t += 256) {
        int kr = t >> 4, n4 = t & 15;
        s16x4 v = *(const s16x4*)&t1s[(size_t)(kc+kr)*128 + j0 + n4*4];
        Bs[(n4*4+0)*72 + kr] = v[0];
        Bs[(n4*4+1)*72 + kr] = v[1];
        Bs[(n4*4+2)*72 + kr] = v[2];
        Bs[(n4*4+3)*72 + kr] = v[3];
      }
      __syncthreads();
      #pragma unroll
      for (int ks = 0; ks < 2; ++ks) {
        short8 a = *(const short8*)&As[(w*16+lane16)*72 + ks*32 + quad*8];
        #pragma unroll
        for (int nt = 0; nt < 4; ++nt) {
          short8 b8 = *(const short8*)&Bs[(nt*16+lane16)*72 + ks*32 + quad*8];
          acc[nt] = __builtin_amdgcn_mfma_f32_16x16x32_bf16(a, b8, acc[nt], 0, 0, 0);
        }
      }
      __syncthreads();
    }
    #pragma unroll
    for (int nt = 0; nt < 4; ++nt)
      #pragma unroll
      for (int r = 0; r < 4; ++r)
        atomicAdd(&ws[OFF_WC + (size_t)(i0 + w*16 + quad*4 + r)*128 + j0 + nt*16 + lane16], acc[nt][r]);
  } else if (blk < 128) {                    // bc = Wb@btmp + bb
    int j = (blk-64)*4 + (tid >> 6), l = tid & 63;
    float s = 0.f;
    for (int c = l; c < 2048; c += 64) s += Wb[(size_t)j*2048 + c] * ws[OFF_BTMP + c];
    for (int off = 32; off; off >>= 1) s += __shfl_down(s, off, 64);
    if (l == 0) ws[OFF_BC + j] = s + bb[j];
  } else {                                   // featp += XPBF @ WBBF^T
    const short* wbbf = (const short*)(ws+OFF_WBBF);
    int idx = blk - 128;                     // 128 tiles: 4 x 4 x 8
    int i0 = (idx & 3)*64, j0 = ((idx >> 2) & 3)*64, kc0 = (idx >> 4)*256;
    int w = tid >> 6, l = tid & 63, quad = l >> 4, lane16 = l & 15;
    f32x4 acc[4];
    #pragma unroll
    for (int i = 0; i < 4; ++i) acc[i] = (f32x4)(0.f);
    for (int kc = kc0; kc < kc0+256; kc += 32) {
      short8 a = *(const short8*)&xpbf[(size_t)(i0 + w*16 + lane16)*2048 + kc + quad*8];
      #pragma unroll
      for (int nt = 0; nt < 4; ++nt) {
        short8 b8 = *(const short8*)&wbbf[(size_t)(j0 + nt*16 + lane16)*2048 + kc + quad*8];
        acc[nt] = __builtin_amdgcn_mfma_f32_16x16x32_bf16(a, b8, acc[nt], 0, 0, 0);
      }
    }
    #pragma unroll
    for (int nt = 0; nt < 4; ++nt)
      #pragma unroll
      for (int r = 0; r < 4; ++r)
        atomicAdd(&featp[(size_t)(i0 + w*16 + quad*4 + r)*256 + j0 + nt*16 + lane16], acc[nt][r]);
  }
}

// ---------------- kpr: pre_output + softmax + 64 PageRank iters (4-way split) ----------------
__global__ __launch_bounds__(384) void kpr(const float* __restrict__ featp,
                                           const float* __restrict__ Wfc,
                                           const float* __restrict__ wpr,
                                           float* __restrict__ preo,
                                           float* __restrict__ vy)
{
  __shared__ alignas(16) float fpr[256];
  __shared__ alignas(16) float po[68];
  __shared__ alignas(16) float vsA[88];
  __shared__ alignas(16) float vsB[88];
  __shared__ alignas(16) float vis[88];
  __shared__ float rd[4];
  int b = blockIdx.x, tid = threadIdx.x;
  if (tid < 256) fpr[tid] = featp[b*256 + tid];
  __syncthreads();
  if (tid < 260) {                            // po: 65 rows x 4-lane split
    int row = tid >> 2, p = tid & 3;
    float s = 0.f;
    const float* wr = Wfc + row*256 + p*64;
    #pragma unroll
    for (int c = 0; c < 64; c += 4) {
      float4 w4 = *(const float4*)&wr[c];
      s += w4.x*fpr[p*64+c] + w4.y*fpr[p*64+c+1] + w4.z*fpr[p*64+c+2] + w4.w*fpr[p*64+c+3];
    }
    s += __shfl_xor(s, 1, 64);
    s += __shfl_xor(s, 2, 64);
    if (p == 0) { po[row] = s; preo[b*65 + row] = s; }
  }
  __syncthreads();
  if (tid < 64) {                             // softmax reduce
    float v = po[tid];
    if (tid == 0) v = fmaxf(v, po[64]);
    float mx = v;
    #pragma unroll
    for (int off = 32; off; off >>= 1) mx = fmaxf(mx, __shfl_down(mx, off, 64));
    mx = __shfl(mx, 0, 64);
    float e = expf(po[tid]-mx) + ((tid == 0) ? expf(po[64]-mx) : 0.f);
    float sm = e;
    #pragma unroll
    for (int off = 32; off; off >>= 1) sm += __shfl_down(sm, off, 64);
    if (tid == 0) { rd[0] = mx; rd[1] = 1.f/sm; }
  }
  __syncthreads();
  if (tid < 88) {
    float vin = (tid >= 22 && tid < 87) ? expf(po[tid-22]-rd[0])*rd[1] : 0.f;
    vis[tid] = vin;
    vsA[tid] = vin * 87.f;
    vsB[tid] = 0.f;
  }
  __syncthreads();
  float wrow[22];
  const int m4 = tid >> 2, pp = tid & 3;
  if (tid < 348) {                            // row m4, k-quarter pp
    float add = vis[m4] * 0.15f;              // = s_i*(0.15/87) with s_i=vinit*87
    #pragma unroll
    for (int jj = 0; jj < 22; ++jj) {
      int j = pp*22 + jj;
      wrow[jj] = (j < 87) ? (wpr[m4*87 + j] + add) : 0.f;
    }
  }
  for (int it = 0; it < 64; ++it) {
    const float* vc = (it & 1) ? vsB : vsA;
    float* vn = (it & 1) ? vsA : vsB;
    if (tid < 348) {
      float nv = 0.f;
      #pragma unroll
      for (int jj = 0; jj < 22; ++jj) nv += wrow[jj] * vc[pp*22 + jj];
      nv += __shfl_xor(nv, 1, 64);
      nv += __shfl_xor(nv, 2, 64);
      if (pp == 0) vn[m4] = nv;
    }
    __syncthreads();
  }
  if (tid < 64) {                             // L2 norm over vsA[0..86]
    float v = vsA[tid]*vsA[tid];
    if (tid < 23) v += vsA[64+tid]*vsA[64+tid];
    #pragma unroll
    for (int off = 32; off; off >>= 1) v += __shfl_down(v, off, 64);
    if (tid == 0) rd[2] = 1.f / fmaxf(sqrtf(v), 1e-12f);
  }
  __syncthreads();
  if (tid < 87) vy[b*87 + tid] = vis[tid] + vsA[tid]*rd[2];
}

// ---------------- knode: 4-way k-split over 256 blocks ----------------
__global__ __launch_bounds__(384) void knode(const float* __restrict__ Wg,
                                             const float* __restrict__ node_p,
                                             const float* __restrict__ vy,
                                             float* __restrict__ nt)
{
  int tid = threadIdx.x;
  if (tid >= 352) return;
  int out = blockIdx.x*88 + (tid >> 2);       // < 22528
  int par = out / 11264;
  int r = out % 11264;
  int o = r / 88, m = r % 88;
  int p = tid & 3;
  float s = 0.f;
  if (m < 87) {
    const float* vrow = vy + (size_t)(par*128)*87 + m;
    for (int k = p*32; k < p*32+32; ++k)
      s += Wg[o*256 + k] * node_p[k*87 + m] * vrow[k*87];
  }
  s += __shfl_xor(s, 1, 64);
  s += __shfl_xor(s, 2, 64);
  if (p == 0) nt[out] = s;
}

// ---------------- kgraph_all: MFMA graph chain + finale, all in LDS ----------------
__global__ __launch_bounds__(512) void kgraph_all(
    const float* __restrict__ part,  const float* __restrict__ b12,
    const short* __restrict__ wapbf, const float* __restrict__ b215,
    const short* __restrict__ wg2bf, const float* __restrict__ nt,
    const float* __restrict__ bg,    const short* __restrict__ enpbf,
    const float* __restrict__ Wsp,   const float* __restrict__ bsp,
    const float* __restrict__ Ws,    const float* __restrict__ wc,
    const float* __restrict__ bc,    const float* __restrict__ featp,
    const float* __restrict__ Wfc2,
    float* __restrict__ feat, float* __restrict__ out2, float* __restrict__ soft)
{
  extern __shared__ char smraw[];
  short* XT = (short*)smraw;             // [64][136]
  short* At = XT + 8704;                 // [224][72]
  short* M1 = At + 16128;                // [96][136]
  short* G  = M1 + 13056;                // [128][104]
  short* M2 = G  + 13312;                // [128][104]
  float* fb  = (float*)(M2 + 13312);
  float* wsm = fb;                       // 96
  float* tnb = fb + 96;                  // 96
  float* zs  = fb + 192;                 // 128
  float* m3s = fb + 320;                 // 128
  float* fs  = fb + 448;                 // 256
  float* o2s = fb + 704;                 // 72
  float* red = fb + 776;                 // 4

  int b = blockIdx.x, tid = threadIdx.x;
  int w = tid >> 6, l = tid & 63, quad = l >> 4, lane16 = l & 15;

  // stage XT[p][c] = bf16(sum of 4 quarter-partials + b12)
  const float* p0 = part + (size_t)b*6656;
  const float* p1 = p0 + (size_t)256*6656;
  const float* p2 = p1 + (size_t)256*6656;
  const float* p3 = p2 + (size_t)256*6656;
  for (int t = tid; t < 6656; t += 512) {
    int o = t / 52, p = t % 52;
    XT[p*136 + o] = (short)f2bf(p0[t] + p1[t] + p2[t] + p3[t] + b12[o]);
  }
  for (int t = tid; t < 1536; t += 512) {        // zero rows p=52..63
    int p = 52 + t/128, o = t % 128;
    XT[p*136 + o] = 0;
  }
  __syncthreads();

  // phase 1a: At[r][p] = Wap @ xl + b215   (M=224, N=64, K=128)
  for (int t = w; t < 56; t += 8) {
    int mt = t >> 2, n4 = t & 3;
    f32x4 acc = (f32x4)(0.f);
    #pragma unroll
    for (int ks = 0; ks < 4; ++ks) {
      short8 a  = *(const short8*)&wapbf[(size_t)(mt*16+lane16)*128 + ks*32 + quad*8];
      short8 b8 = *(const short8*)&XT[(n4*16+lane16)*136 + ks*32 + quad*8];
      acc = __builtin_amdgcn_mfma_f32_16x16x32_bf16(a, b8, acc, 0, 0, 0);
    }
    int p = n4*16 + lane16;
    #pragma unroll
    for (int r = 0; r < 4; ++r) {
      int rr = mt*16 + quad*4 + r;
      At[rr*72 + p] = (p < 49) ? (short)f2bf(acc[r] + b215[rr]) : (short)0;
    }
  }
  __syncthreads();

  // phase 1b: M1[m][d] = relu(a-rows @ ps-rows^T)   (M=96, N=128, K=64)
  for (int t = w; t < 48; t += 8) {
    int mt = t / 8, n4 = t % 8;
    f32x4 acc = (f32x4)(0.f);
    #pragma unroll
    for (int ks = 0; ks < 2; ++ks) {
      short8 a  = *(const short8*)&At[(128 + mt*16 + lane16)*72 + ks*32 + quad*8];
      short8 b8 = *(const short8*)&At[(n4*16+lane16)*72 + ks*32 + quad*8];
      acc = __builtin_amdgcn_mfma_f32_16x16x32_bf16(a, b8, acc, 0, 0, 0);
    }
    int d = n4*16 + lane16;
    #pragma unroll
    for (int r = 0; r < 4; ++r) {
      int m = mt*16 + quad*4 + r;
      M1[m*136 + d] = (short)f2bf(fmaxf(acc[r], 0.f));
    }
  }
  __syncthreads();

  // phase 2: G[o][m] = Wg2 @ m1 + nt + bg   (M=128, N=96, K=128)
  const float* ntb = nt + (size_t)(b & 1)*11264;
  for (int t = w; t < 48; t += 8) {
    int mt = t / 6, n4 = t % 6;
    f32x4 acc = (f32x4)(0.f);
    #pragma unroll
    for (int ks = 0; ks < 4; ++ks) {
      short8 a  = *(const short8*)&wg2bf[(size_t)(mt*16+lane16)*128 + ks*32 + quad*8];
      short8 b8 = *(const short8*)&M1[(n4*16+lane16)*136 + ks*32 + quad*8];
      acc = __builtin_amdgcn_mfma_f32_16x16x32_bf16(a, b8, acc, 0, 0, 0);
    }
    int m = n4*16 + lane16;
    #pragma unroll
    for (int r = 0; r < 4; ++r) {
      int o = mt*16 + quad*4 + r;
      float v = acc[r] + bg[o] + ((m < 88) ? ntb[o*88 + m] : 0.f);
      G[o*104 + m] = (short)f2bf(v);
    }
  }
  __syncthreads();

  // phase 3: M2[c][n] = relu(G @ enp)   (M=128, N=96, K=96; enp symmetric)
  for (int t = w; t < 48; t += 8) {
    int mt = t / 6, n4 = t % 6;
    f32x4 acc = (f32x4)(0.f);
    #pragma unroll
    for (int ks = 0; ks < 3; ++ks) {
      short8 a  = *(const short8*)&G[(mt*16+lane16)*104 + ks*32 + quad*8];
      short8 b8 = *(const short8*)&enpbf[(size_t)(n4*16+lane16)*96 + ks*32 + quad*8];
      acc = __builtin_amdgcn_mfma_f32_16x16x32_bf16(a, b8, acc, 0, 0, 0);
    }
    int n = n4*16 + lane16;
    #pragma unroll
    for (int r = 0; r < 4; ++r) {
      int c = mt*16 + quad*4 + r;
      M2[c*104 + n] = (short)f2bf(fmaxf(acc[r], 0.f));
    }
  }
  __syncthreads();

  // phase 4: node softmax + m3 (serial chains split 4-way across lanes)
  if (tid < 348) {                            // tnb[m] = Ws . M2[:,m]
    int m = tid >> 2, p = tid & 3;
    float s = 0.f;
    for (int c = p*32; c < p*32+32; ++c)
      s += Ws[c] * bf2f((unsigned short)M2[c*104 + m]);
    s += __shfl_xor(s, 1, 64);
    s += __shfl_xor(s, 2, 64);
    if (p == 0) tnb[m] = s;
  }
  __syncthreads();
  if (tid < 64) {
    float v = tnb[tid];
    if (tid < 23) v = fmaxf(v, tnb[64+tid]);
    float mx = v;
    #pragma unroll
    for (int off = 32; off; off >>= 1) mx = fmaxf(mx, __shfl_down(mx, off, 64));
    mx = __shfl(mx, 0, 64);
    float e0 = expf(tnb[tid]-mx);
    float e1 = (tid < 23) ? expf(tnb[64+tid]-mx) : 0.f;
    float sm = e0 + e1;
    #pragma unroll
    for (int off = 32; off; off >>= 1) sm += __shfl_down(sm, off, 64);
    sm = __shfl(sm, 0, 64);
    float inv = 1.f/sm;
    wsm[tid] = e0*inv;
    if (tid < 23) wsm[64+tid] = e1*inv;
  }
  __syncthreads();
  {                                           // zs[c] = M2[c,:] . wsm
    int c = tid >> 2, p = tid & 3;
    float s = 0.f;
    for (int mm = p*22; mm < p*22+22 && mm < 87; ++mm)
      s += bf2f((unsigned short)M2[c*104 + mm]) * wsm[mm];
    s += __shfl_xor(s, 1, 64);
    s += __shfl_xor(s, 2, 64);
    if (p == 0) zs[c] = s;
  }
  __syncthreads();
  {                                           // m3s[d] = relu(Wsp[d,:] . zs + bsp)
    int d = tid >> 2, p = tid & 3;
    float s = 0.f;
    for (int c = p*32; c < p*32+32; ++c) s += Wsp[d*128 + c] * zs[c];
    s += __shfl_xor(s, 1, 64);
    s += __shfl_xor(s, 2, 64);
    if (p == 0) m3s[d] = fmaxf(s + bsp[d], 0.f);
  }
  __syncthreads();

  // phase 5: features / outputs2 / softmax
  if (tid < 256) {
    float s = 0.f;
    #pragma unroll 4
    for (int d4 = 0; d4 < 32; ++d4) {
      float4 w4 = *(const float4*)&wc[tid*128 + d4*4];
      s += w4.x*m3s[d4*4] + w4.y*m3s[d4*4+1] + w4.z*m3s[d4*4+2] + w4.w*m3s[d4*4+3];
    }
    float f = featp[b*256 + tid] + bc[tid] + s;
    fs[tid] = f;
    feat[b*256 + tid] = f;
  }
  __syncthreads();
  if (tid < 260) {                            // out2: 65 rows x 4-lane split
    int row = tid >> 2, p = tid & 3;
    float s = 0.f;
    for (int c = p*64; c < p*64+64; c += 4) {
      float4 w4 = *(const float4*)&Wfc2[row*256 + c];
      s += w4.x*fs[c] + w4.y*fs[c+1] + w4.z*fs[c+2] + w4.w*fs[c+3];
    }
    s += __shfl_xor(s, 1, 64);
    s += __shfl_xor(s, 2, 64);
    if (p == 0) { out2[b*65 + row] = s; o2s[row] = s; }
  }
  __syncthreads();
  if (tid < 64) {
    float v = o2s[tid];
    if (tid == 0) v = fmaxf(v, o2s[64]);
    float mx = v;
    #pragma unroll
    for (int off = 32; off; off >>= 1) mx = fmaxf(mx, __shfl_down(mx, off, 64));
    mx = __shfl(mx, 0, 64);
    float e = expf(o2s[tid]-mx) + ((tid == 0) ? expf(o2s[64]-mx) : 0.f);
    float sm = e;
    #pragma unroll
    for (int off = 32; off; off >>= 1) sm += __shfl_down(sm, off, 64);
    if (tid == 0) { red[0] = mx; red[1] = 1.f/sm; }
  }
  __syncthreads();
  if (tid < 65) soft[b*65 + tid] = expf(o2s[tid]-red[0]) * red[1];
}

// ---------------- launch ----------------
extern "C" void kernel_launch(void* const* d_in, const int* in_sizes, int n_in,
                              void* d_out, int out_size, void* d_ws, size_t ws_size,
                              hipStream_t stream)
{
  (void)in_sizes; (void)n_in; (void)out_size; (void)ws_size;
  const float* x      = (const float*)d_in[0];
  const float* Wb     = (const float*)d_in[1];
  const float* bb     = (const float*)d_in[2];
  const float* Wfc    = (const float*)d_in[3];
  const float* Wfc2   = (const float*)d_in[4];
  const float* Wo1    = (const float*)d_in[5];
  const float* bo1    = (const float*)d_in[6];
  const float* Wo2    = (const float*)d_in[7];
  const float* bo2    = (const float*)d_in[8];
  const float* Wa     = (const float*)d_in[9];
  const float* ba     = (const float*)d_in[10];
  const float* Wps    = (const float*)d_in[11];
  const float* bps    = (const float*)d_in[12];
  const float* node_p = (const float*)d_in[13];
  const float* Wg     = (const float*)d_in[14];
  const float* bg     = (const float*)d_in[15];
  const float* Wsp    = (const float*)d_in[16];
  const float* bsp    = (const float*)d_in[17];
  const float* Ws     = (const float*)d_in[18];
  const float* Wox1   = (const float*)d_in[20];
  const float* box1   = (const float*)d_in[21];
  const float* Wox2   = (const float*)d_in[22];
  const float* box2   = (const float*)d_in[23];
  const float* edge   = (const float*)d_in[24];

  float* ws   = (float*)d_ws;
  float* out  = (float*)d_out;
  float* feat  = out;            // (256,256)
  float* out2  = out + 65536;    // (256,65)
  float* soft  = out + 82176;    // (256,65)
  float* preo  = out + 98816;    // (256,65)
  float* featp = out + 115456;   // (256,256)

  ksetup_all<<<1135, 256, 0, stream>>>(Wb, bb, Wa, ba, Wps, bps, Wg, edge,
                                       Wo2, Wo1, Wox2, Wox1, box1, box2, bo1, bo2,
                                       ws, featp);
  kmain5<<<dim3(256,4), 512, 0, stream>>>(x, (const short*)(ws + OFF_W12BF),
                                          (short*)(ws + OFF_XPBF), ws + OFF_PART);
  kwcf<<<256, 256, 0, stream>>>(Wb, bb, (const short*)(ws + OFF_XPBF), featp, ws);
  kpr<<<256, 384, 0, stream>>>(featp, Wfc, ws + OFF_WPR, preo, ws + OFF_VY);
  knode<<<256, 384, 0, stream>>>(Wg, node_p, ws + OFF_VY, ws + OFF_NT);
  kgraph_all<<<256, 512, 132144, stream>>>(ws + OFF_PART, ws + OFF_B12,
                                           (const short*)(ws + OFF_WAPBF),
                                           ws + OFF_B215,
                                           (const short*)(ws + OFF_WG2BF),
                                           ws + OFF_NT, bg,
                                           (const short*)(ws + OFF_ENPBF),
                                           Wsp, bsp, Ws,
                                           ws + OFF_WC, ws + OFF_BC, featp, Wfc2,
                                           feat, out2, soft);
}